// Round 8
// baseline (353.284 us; speedup 1.0000x reference)
//
#include <hip/hip_runtime.h>
#include <hip/hip_cooperative_groups.h>
#include <hip/hip_bf16.h>
#include <math.h>

namespace cg = cooperative_groups;

// Problem constants
#define SEQ   4096
#define DIM   512
#define BW    24            // band half-width: prior underflows fp32 beyond |i-j|~20
#define NDIAG 49            // 2*BW+1
#define TW    56            // padded tap width (49 -> 56 for 16B alignment)
#define VSTR  4608          // padded row stride for vectors (4096 + 512)
#define VOFF  256           // data offset inside padded row (zeros on both sides)
#define INV_N (1.0f/4096.0f)

// ws layout in floats (~31.4 MB; ws is ~268 MB per harness poison fill)
#define OFF_KT   0                          // Kt fp32 [2][4096][56]: taps for N-step
#define SZ_T     (2*SEQ*TW)                 // 458752
#define OFF_KC   (OFF_KT + SZ_T)            // Kc fp32 [2][4096][56]: taps for T-step
#define OFF_DT   (OFF_KC + SZ_T)            // Dt fp32 [2][4096][56]
#define OFF_VEC  (OFF_DT + SZ_T)            // 6 padded vectors: u(g0,g1), y(g0,g1), v(g0,g1)
#define SZ_VEC   (6*VSTR)
#define OFF_PX   (OFF_VEC + SZ_VEC)         // pMp for P,Q,R,S : 4 x 4096
#define SZ_PX    (4*SEQ)
#define OFF_SC   (OFF_PX + SZ_PX)           // scalars: [0,1]=crit g0/g1, [2,3]=S g0/g1
#define SZ_SC    16
#define OFF_BBF  (OFF_SC + SZ_SC)           // Bsym bf16 512x512
#define SZ_BBF   (DIM*DIM/2)
#define OFF_XBF  (OFF_BBF + SZ_BBF)         // P,Q,R,S bf16: 4 x 4096 x 512
#define SZ_XBF   (4*SEQ*DIM/2)
#define OFF_GBF  (OFF_XBF + SZ_XBF)         // P@B, R@B bf16
#define SZ_GBF   (2*SEQ*DIM/2)
#define WS_FLOATS (OFF_GBF + SZ_GBF)

typedef __attribute__((ext_vector_type(8))) short short8;
typedef __attribute__((ext_vector_type(4))) float f32x4;

__device__ __forceinline__ ushort f2bfh(float f) {
    __hip_bfloat16 h = __float2bfloat16(f);      // native v_cvt (RNE)
    return *reinterpret_cast<ushort*>(&h);
}
__device__ __forceinline__ float bf2f(ushort u) {
    union { unsigned u; float f; } w; w.u = ((unsigned)u) << 16; return w.f;
}

__device__ __forceinline__ void gload16(void* lds, const void* g) {
    __builtin_amdgcn_global_load_lds(
        (const __attribute__((address_space(1))) unsigned int*)g,
        (__attribute__((address_space(3))) unsigned int*)lds,
        16, 0, 0);
}

// ---------------- fused prep: zero bands+vec+pX+sc, Bbf = bf16(M+M^T), Xbf cvt (P,Q,R,S) ----------------
#define ZQUADS (OFF_BBF/4)
#define ZBLK   ((ZQUADS + 255)/256)
#define BBLK   1024
#define CBLK   8192                          // 4 arrays x 2048 blocks
#define PREP_BLOCKS (ZBLK + BBLK + CBLK)

__global__ void kprep(const float* __restrict__ P, const float* __restrict__ Q,
                      const float* __restrict__ R, const float* __restrict__ S,
                      const float* __restrict__ M, float* __restrict__ ws) {
    int b = blockIdx.x, tid = threadIdx.x;
    if (b < ZBLK) {
        int q = b*256 + tid;
        if (q < ZQUADS)
            *reinterpret_cast<float4*>(&ws[(size_t)q*4]) = (float4){0.f,0.f,0.f,0.f};
    } else if (b < ZBLK + BBLK) {
        int idx = (b - ZBLK)*256 + tid;
        int d = idx >> 9, e = idx & 511;
        ((ushort*)(ws + OFF_BBF))[idx] = f2bfh(M[d*DIM + e] + M[e*DIM + d]);
    } else {
        int cb = b - (ZBLK + BBLK);
        int z = cb >> 11;
        const float* src = (z==0) ? P : (z==1) ? Q : (z==2) ? R : S;
        size_t idx = ((size_t)(cb & 2047)*256 + tid)*4;
        float4 v = *reinterpret_cast<const float4*>(&src[idx]);
        ushort4 o;
        o.x = f2bfh(v.x); o.y = f2bfh(v.y); o.z = f2bfh(v.z); o.w = f2bfh(v.w);
        *reinterpret_cast<ushort4*>(((ushort*)(ws + OFF_XBF)) + (size_t)z*SEQ*DIM + idx) = o;
    }
}

// ---------------- MFMA GEMM, all-bf16 A, 2-phase pipelined (verified r7) ----------------
__launch_bounds__(256, 4)
__global__ void kgemm5(const ushort* __restrict__ Xbf, const ushort* __restrict__ Bbf,
                       ushort* __restrict__ GBbf, float* __restrict__ pX) {
    int z = blockIdx.z;
    const ushort* Xh = Xbf + (size_t)z*SEQ*DIM;
    int i0 = blockIdx.x * 128;
    int j0 = blockIdx.y * 128;
    __shared__ ushort As[2*4096];      // 2 x 8KB, chunk-major
    __shared__ ushort Bs[2*4096];      // 2 x 8KB, rows 64B, chunk^=(col&3)
    int tid = threadIdx.x, wv = tid >> 6, l = tid & 63;
    int h = l >> 4, lr = l & 15;
    int wrow = (wv >> 1)*64, wcol = (wv & 1)*64;

    auto stageA = [&](int buf, int kc) {
        #pragma unroll
        for (int s2 = 0; s2 < 2; ++s2) {
            int seg = wv*2 + s2;               // chunk = seg>>1, rowhalf = seg&1
            gload16((char*)As + (size_t)buf*8192 + seg*1024,
                    &Xh[(size_t)(i0 + (seg&1)*64 + l)*DIM + kc + (seg>>1)*8]);
        }
    };
    auto stageB = [&](int buf, int kc) {
        #pragma unroll
        for (int s2 = 0; s2 < 2; ++s2) {
            int seg = wv*2 + s2;
            int col = seg*16 + (l >> 2);
            int cs = (l & 3) ^ (col & 3);
            gload16((char*)Bs + (size_t)buf*8192 + seg*1024,
                    &Bbf[(size_t)(j0+col)*DIM + kc + cs*8]);
        }
    };

    f32x4 acc[4][4];
    #pragma unroll
    for (int a = 0; a < 4; ++a)
        #pragma unroll
        for (int b = 0; b < 4; ++b) acc[a][b] = (f32x4){0.f,0.f,0.f,0.f};

    stageA(0, 0); stageB(0, 0);
    __syncthreads();
    for (int t = 0; t < 16; ++t) {
        int cur = t & 1;
        if (t < 15) { stageA(cur ^ 1, (t+1)*32); stageB(cur ^ 1, (t+1)*32); }
        short8 a8[4], b8[4];
        #pragma unroll
        for (int rt = 0; rt < 4; ++rt) {
            int row = wrow + rt*16 + lr;
            a8[rt] = *reinterpret_cast<const short8*>(
                (const char*)As + (size_t)cur*8192 + h*2048 + row*16);
        }
        #pragma unroll
        for (int ct = 0; ct < 4; ++ct) {
            int col = wcol + ct*16 + lr;
            int c = h ^ (col & 3);
            b8[ct] = *reinterpret_cast<const short8*>(
                (const char*)Bs + (size_t)cur*8192 + col*64 + c*16);
        }
        #pragma unroll
        for (int rt = 0; rt < 4; ++rt)
            #pragma unroll
            for (int ct = 0; ct < 4; ++ct)
                acc[rt][ct] = __builtin_amdgcn_mfma_f32_16x16x32_bf16(a8[rt], b8[ct], acc[rt][ct], 0, 0, 0);
        __syncthreads();
    }

    // epilogue: rowdot + GBbf store (z even)
    #pragma unroll
    for (int rt = 0; rt < 4; ++rt) {
        #pragma unroll
        for (int r = 0; r < 4; ++r) {
            int row = wrow + rt*16 + h*4 + r;
            float v = 0.f;
            #pragma unroll
            for (int ct = 0; ct < 4; ++ct) {
                int col = wcol + ct*16 + lr;
                float cv = acc[rt][ct][r];
                float xv = bf2f(Xh[(size_t)(i0+row)*DIM + j0 + col]);
                v = fmaf(cv, xv, v);
                if ((z & 1) == 0)
                    GBbf[((size_t)((z>>1)*SEQ + i0 + row))*DIM + j0 + col] = f2bfh(cv);
            }
            v += __shfl_xor(v, 1); v += __shfl_xor(v, 2);
            v += __shfl_xor(v, 4); v += __shfl_xor(v, 8);
            if (lr == 0) atomicAdd(&pX[(size_t)z*SEQ + i0 + row], 0.5f*v);
        }
    }
}

// ---------------- band via MFMA -> row-major fp32 taps Kt/Kc + Dt (verified r7) ----------------
__launch_bounds__(64)
__global__ void kband3(const ushort* __restrict__ GBbf, const ushort* __restrict__ Xbf,
                       const float* __restrict__ pX,
                       float* __restrict__ Ktb, float* __restrict__ Kcb,
                       float* __restrict__ Dt) {
    int g = blockIdx.y;
    int i0 = blockIdx.x * 16;
    int l = threadIdx.x;
    const ushort* A = GBbf + (size_t)g*SEQ*DIM;
    const ushort* Y = Xbf + (size_t)(1 + 2*g)*SEQ*DIM;      // Q for g0, S for g1
    const float* pM = pX + (size_t)(2*g)*SEQ;
    const float* qM = pX + (size_t)(2*g+1)*SEQ;
    int jbase = i0 - BW;
    int arow = i0 + (l & 15);
    int koff = (l >> 4) * 8;
    int jcl[4];
    #pragma unroll
    for (int ct = 0; ct < 4; ++ct) {
        int j = jbase + ct*16 + (l & 15);
        jcl[ct] = min(max(j, 0), SEQ-1);
    }
    f32x4 acc[4];
    #pragma unroll
    for (int ct = 0; ct < 4; ++ct) acc[ct] = (f32x4){0.f,0.f,0.f,0.f};
    #pragma unroll
    for (int ks = 0; ks < 16; ++ks) {
        int kk = ks*32 + koff;
        short8 af = *reinterpret_cast<const short8*>(&A[(size_t)arow*DIM + kk]);
        #pragma unroll
        for (int ct = 0; ct < 4; ++ct) {
            short8 bf = *reinterpret_cast<const short8*>(&Y[(size_t)jcl[ct]*DIM + kk]);
            acc[ct] = __builtin_amdgcn_mfma_f32_16x16x32_bf16(af, bf, acc[ct], 0, 0, 0);
        }
    }
    #pragma unroll
    for (int ct = 0; ct < 4; ++ct) {
        #pragma unroll
        for (int r = 0; r < 4; ++r) {
            int i = i0 + (l >> 4)*4 + r;
            int j = jbase + ct*16 + (l & 15);
            int d = j - i;
            if (d >= -BW && d <= BW && j >= 0 && j < SEQ) {
                float dist = pM[i] + qM[j] - acc[ct][r];
                float fd = (float)d;
                float rel = fd * (1.0f/4096.0f);
                float cd = -0.91893853f - 0.25f*fd*fd + 1e-4f/(rel*rel + 1.0f);
                float Kv = expf(cd - dist*1e-3f);
                Ktb[((size_t)g*SEQ + i)*TW + (d + BW)] = Kv;
                Kcb[((size_t)g*SEQ + j)*TW + (BW - d)] = Kv;
                Dt [((size_t)g*SEQ + i)*TW + (d + BW)] = dist;
            }
        }
    }
}

// ---------------- Sinkhorn (cooperative): 42 steps as 7 supersteps + final reduce ----------------
// Identical math/schedule to the verified 8-launch chain; grid.sync() replaces kernel boundaries.
#define SR3  32
#define SB3  384          // covers range0(368 max) + tap-pad overread (taps 49..55 are zero)
#define NSS  7
__launch_bounds__(256, 4)
__global__ void ksinkcoop(const float* __restrict__ Ktb, const float* __restrict__ Kcb,
                          const float* __restrict__ Dt, float* __restrict__ vecs,
                          float* __restrict__ sc, float* __restrict__ out) {
    cg::grid_group grid = cg::this_grid();
    const int NS[NSS] = {5,6,6,6,6,6,7};
    const int FT[NSS] = {1,0,0,0,0,0,0};
    const int AI[NSS] = {1,0,0,0,0,0,0};
    const int VS[NSS] = {2,-1,-1,-1,-1,-1,5};
    const int US[NSS] = {3,-1,-1,-1,-1,-1,-1};
    const int CS[NSS] = {4,-1,-1,-1,-1,-1,-1};
    const int IN[NSS] = {0,1,1,1,1,1,1};
    const int OU[NSS] = {1,1,1,1,1,1,0};
    int g = blockIdx.y;
    int r0 = blockIdx.x * SR3;
    __shared__ float bufA[SB3];
    __shared__ float bufB[SB3];
    __shared__ float vsave[SB3];
    __shared__ float red[256];
    bool skip = false;

    for (int ss = 0; ss < NSS; ++ss) {
        if (!(ss > 0 && skip)) {
            int nsteps = NS[ss];
            int vstep = VS[ss], ustep = US[ss], cstep = CS[ss];
            int ext = 24*nsteps;
            int base = r0 - ext;
            int range0 = SR3 + 2*ext;
            const float* vin = vecs + (size_t)(IN[ss]*2 + g)*VSTR;
            for (int L = threadIdx.x; L < SB3; L += 256) {
                int gr = base + L;
                float v = 0.f;
                if (L < range0 && gr >= 0 && gr < SEQ)
                    v = AI[ss] ? (gr+1)*INV_N : vin[VOFF + gr];
                bufA[L] = v;
                bufB[L] = 0.f;
            }
            __syncthreads();
            float critloc = 0.f;
            float* bin = bufA;
            float* bout = bufB;
            for (int m = 0; m < nsteps; ++m) {
                int e = 24*(nsteps - 1 - m);
                int lo = ext - e;
                int cnt = SR3 + 2*e;
                int typeT = FT[ss] ^ (m & 1);
                const float* tap0 = (typeT ? Kcb : Ktb) + (size_t)g*SEQ*TW;
                for (int t = threadIdx.x; t < cnt; t += 256) {
                    int L = lo + t;
                    int gr = base + L;
                    float o = 0.f;
                    if (gr >= 0 && gr < SEQ) {
                        const float* tap = tap0 + (size_t)gr*TW;
                        float s = 0.f;
                        #pragma unroll
                        for (int c = 0; c < 14; ++c) {
                            float4 k4 = *reinterpret_cast<const float4*>(tap + c*4);
                            s = fmaf(k4.x, bin[L + c*4 + 0 - BW], s);
                            s = fmaf(k4.y, bin[L + c*4 + 1 - BW], s);
                            s = fmaf(k4.z, bin[L + c*4 + 2 - BW], s);
                            s = fmaf(k4.w, bin[L + c*4 + 3 - BW], s);
                        }
                        float ab = (gr+1)*INV_N;      // alpha == beta (m==n)
                        o = ab * __builtin_amdgcn_rcpf(s);
                        if (m == vstep) {
                            vecs[(size_t)(4 + g)*VSTR + VOFF + gr] = o;      // v slot
                            if (cstep >= 0) vsave[L] = o;
                        }
                        if (m == ustep)
                            vecs[(size_t)g*VSTR + VOFF + gr] = o;            // u slot
                        if (m == cstep)
                            critloc += fabsf(vsave[L]*s - ab);
                    }
                    bout[L] = o;
                }
                __syncthreads();
                float* tmp = bin; bin = bout; bout = tmp;
            }
            if (threadIdx.x < SR3) {
                int gr = r0 + threadIdx.x;
                vecs[(size_t)(OU[ss]*2 + g)*VSTR + VOFF + gr] = bin[ext + threadIdx.x];
            }
            if (cstep >= 0) {
                red[threadIdx.x] = critloc;
                __syncthreads();
                for (int s2 = 128; s2 > 0; s2 >>= 1) {
                    if (threadIdx.x < s2) red[threadIdx.x] += red[threadIdx.x + s2];
                    __syncthreads();
                }
                if (threadIdx.x == 0) atomicAdd(&sc[g], red[0]);
            }
        }
        grid.sync();
        if (ss == 0) skip = (sc[g] < 1e-5f);
    }

    // final: S_g = sum_i u_i * sum_t Kt[i][t]*Dt[i][t]*v[i+t-BW]  (this block's 32 rows)
    {
        float partial = 0.f;
        if (threadIdx.x < SR3) {
            int i = r0 + threadIdx.x;
            const float* kt = Ktb + ((size_t)g*SEQ + i)*TW;
            const float* dt = Dt  + ((size_t)g*SEQ + i)*TW;
            const float* u = vecs + (size_t)g*VSTR + VOFF;
            const float* v = vecs + (size_t)(4 + g)*VSTR + VOFF;
            float ssum = 0.f;
            #pragma unroll
            for (int c = 0; c < 14; ++c) {
                float4 k4 = *reinterpret_cast<const float4*>(kt + c*4);
                float4 d4 = *reinterpret_cast<const float4*>(dt + c*4);
                ssum += k4.x * d4.x * v[i + c*4 + 0 - BW];
                ssum += k4.y * d4.y * v[i + c*4 + 1 - BW];
                ssum += k4.z * d4.z * v[i + c*4 + 2 - BW];
                ssum += k4.w * d4.w * v[i + c*4 + 3 - BW];
            }
            partial = ssum * u[i];
        }
        red[threadIdx.x] = partial;
        __syncthreads();
        for (int s2 = 128; s2 > 0; s2 >>= 1) {
            if (threadIdx.x < s2) red[threadIdx.x] += red[threadIdx.x + s2];
            __syncthreads();
        }
        if (threadIdx.x == 0) atomicAdd(&sc[2+g], red[0]);
    }
    grid.sync();
    if (blockIdx.x == 0 && blockIdx.y == 0 && threadIdx.x == 0)
        out[0] = sc[2] - sc[3];
}

extern "C" void kernel_launch(void* const* d_in, const int* in_sizes, int n_in,
                              void* d_out, int out_size, void* d_ws, size_t ws_size,
                              hipStream_t stream) {
    const float* P = (const float*)d_in[0];
    const float* Q = (const float*)d_in[1];
    const float* R = (const float*)d_in[2];
    const float* S = (const float*)d_in[3];
    const float* M = (const float*)d_in[4];
    float* ws = (float*)d_ws;
    if (ws_size < (size_t)WS_FLOATS * sizeof(float)) return;

    float*  Ktb = ws + OFF_KT;
    float*  Kcb = ws + OFF_KC;
    float*  Dt  = ws + OFF_DT;
    float*  vec = ws + OFF_VEC;
    float*  pX  = ws + OFF_PX;
    float*  sc  = ws + OFF_SC;
    ushort* Bbf = (ushort*)(ws + OFF_BBF);
    ushort* Xbf = (ushort*)(ws + OFF_XBF);
    ushort* GBbf= (ushort*)(ws + OFF_GBF);

    kprep <<<dim3(PREP_BLOCKS), dim3(256), 0, stream>>>(P, Q, R, S, M, ws);
    kgemm5<<<dim3(32, 4, 4),    dim3(256), 0, stream>>>(Xbf, Bbf, GBbf, pX);
    kband3<<<dim3(256, 2),      dim3(64),  0, stream>>>(GBbf, Xbf, pX, Ktb, Kcb, Dt);

    // Entire Sinkhorn (42 steps) + final contraction + output in ONE cooperative kernel.
    float* outp = (float*)d_out;
    void* args[] = { (void*)&Ktb, (void*)&Kcb, (void*)&Dt,
                     (void*)&vec, (void*)&sc, (void*)&outp };
    hipLaunchCooperativeKernel((void*)ksinkcoop, dim3(128, 2), dim3(256),
                               args, 0, stream);
}

// Round 9
// 169.051 us; speedup vs baseline: 2.0898x; 2.0898x over previous
//
#include <hip/hip_runtime.h>
#include <hip/hip_bf16.h>
#include <math.h>

// Problem constants
#define SEQ   4096
#define DIM   512
#define BW    24            // band half-width: prior underflows fp32 beyond |i-j|~20
#define NDIAG 49            // 2*BW+1
#define TW    56            // padded tap width (49 -> 56 for 16B alignment)
#define VSTR  4608          // padded row stride for vectors (4096 + 512)
#define VOFF  256           // data offset inside padded row (zeros on both sides)
#define INV_N (1.0f/4096.0f)

// ws layout in floats
#define OFF_KT   0                          // Kt fp32 [2][4096][56]: taps for N-step
#define SZ_T     (2*SEQ*TW)                 // 458752
#define OFF_KC   (OFF_KT + SZ_T)            // Kc fp32 [2][4096][56]: taps for T-step
#define OFF_DT   (OFF_KC + SZ_T)            // Dt fp32 [2][4096][56]
#define OFF_VEC  (OFF_DT + SZ_T)            // 6 padded vectors: u(g0,g1), y(g0,g1), v(g0,g1)
#define SZ_VEC   (6*VSTR)
#define OFF_PX   (OFF_VEC + SZ_VEC)         // pMp for P,Q,R,S : 4 x 4096
#define SZ_PX    (4*SEQ)
#define OFF_SC   (OFF_PX + SZ_PX)           // scalars: [0,1]=crit, [2,3]=S, [4]=done-counter
#define SZ_SC    16
#define OFF_BBF  (OFF_SC + SZ_SC)           // Bsym bf16 512x512
#define SZ_BBF   (DIM*DIM/2)
#define OFF_XBF  (OFF_BBF + SZ_BBF)         // P,Q,R,S bf16: 4 x 4096 x 512
#define SZ_XBF   (4*SEQ*DIM/2)
#define OFF_GBF  (OFF_XBF + SZ_XBF)         // P@B, R@B bf16
#define SZ_GBF   (2*SEQ*DIM/2)
#define WS_FLOATS (OFF_GBF + SZ_GBF)

typedef __attribute__((ext_vector_type(8))) short short8;
typedef __attribute__((ext_vector_type(4))) float f32x4;

__device__ __forceinline__ ushort f2bfh(float f) {
    __hip_bfloat16 h = __float2bfloat16(f);      // native v_cvt (RNE)
    return *reinterpret_cast<ushort*>(&h);
}
__device__ __forceinline__ float bf2f(ushort u) {
    union { unsigned u; float f; } w; w.u = ((unsigned)u) << 16; return w.f;
}

__device__ __forceinline__ void gload16(void* lds, const void* g) {
    __builtin_amdgcn_global_load_lds(
        (const __attribute__((address_space(1))) unsigned int*)g,
        (__attribute__((address_space(3))) unsigned int*)lds,
        16, 0, 0);
}

// ---------------- fused prep: zero taps+vec+pX+sc, Bbf = bf16(M+M^T), Xbf cvt (verified r7) ----------------
#define ZQUADS (OFF_BBF/4)
#define ZBLK   ((ZQUADS + 255)/256)
#define BBLK   1024
#define CBLK   8192
#define PREP_BLOCKS (ZBLK + BBLK + CBLK)

__global__ void kprep(const float* __restrict__ P, const float* __restrict__ Q,
                      const float* __restrict__ R, const float* __restrict__ S,
                      const float* __restrict__ M, float* __restrict__ ws) {
    int b = blockIdx.x, tid = threadIdx.x;
    if (b < ZBLK) {
        int q = b*256 + tid;
        if (q < ZQUADS)
            *reinterpret_cast<float4*>(&ws[(size_t)q*4]) = (float4){0.f,0.f,0.f,0.f};
    } else if (b < ZBLK + BBLK) {
        int idx = (b - ZBLK)*256 + tid;
        int d = idx >> 9, e = idx & 511;
        ((ushort*)(ws + OFF_BBF))[idx] = f2bfh(M[d*DIM + e] + M[e*DIM + d]);
    } else {
        int cb = b - (ZBLK + BBLK);
        int z = cb >> 11;
        const float* src = (z==0) ? P : (z==1) ? Q : (z==2) ? R : S;
        size_t idx = ((size_t)(cb & 2047)*256 + tid)*4;
        float4 v = *reinterpret_cast<const float4*>(&src[idx]);
        ushort4 o;
        o.x = f2bfh(v.x); o.y = f2bfh(v.y); o.z = f2bfh(v.z); o.w = f2bfh(v.w);
        *reinterpret_cast<ushort4*>(((ushort*)(ws + OFF_XBF)) + (size_t)z*SEQ*DIM + idx) = o;
    }
}

// ---------------- MFMA GEMM, all-bf16 A, 2-phase pipelined (verified r7) ----------------
__launch_bounds__(256, 4)
__global__ void kgemm5(const ushort* __restrict__ Xbf, const ushort* __restrict__ Bbf,
                       ushort* __restrict__ GBbf, float* __restrict__ pX) {
    int z = blockIdx.z;
    const ushort* Xh = Xbf + (size_t)z*SEQ*DIM;
    int i0 = blockIdx.x * 128;
    int j0 = blockIdx.y * 128;
    __shared__ ushort As[2*4096];      // 2 x 8KB, chunk-major
    __shared__ ushort Bs[2*4096];      // 2 x 8KB, rows 64B, chunk^=(col&3)
    int tid = threadIdx.x, wv = tid >> 6, l = tid & 63;
    int h = l >> 4, lr = l & 15;
    int wrow = (wv >> 1)*64, wcol = (wv & 1)*64;

    auto stageA = [&](int buf, int kc) {
        #pragma unroll
        for (int s2 = 0; s2 < 2; ++s2) {
            int seg = wv*2 + s2;               // chunk = seg>>1, rowhalf = seg&1
            gload16((char*)As + (size_t)buf*8192 + seg*1024,
                    &Xh[(size_t)(i0 + (seg&1)*64 + l)*DIM + kc + (seg>>1)*8]);
        }
    };
    auto stageB = [&](int buf, int kc) {
        #pragma unroll
        for (int s2 = 0; s2 < 2; ++s2) {
            int seg = wv*2 + s2;
            int col = seg*16 + (l >> 2);
            int cs = (l & 3) ^ (col & 3);
            gload16((char*)Bs + (size_t)buf*8192 + seg*1024,
                    &Bbf[(size_t)(j0+col)*DIM + kc + cs*8]);
        }
    };

    f32x4 acc[4][4];
    #pragma unroll
    for (int a = 0; a < 4; ++a)
        #pragma unroll
        for (int b = 0; b < 4; ++b) acc[a][b] = (f32x4){0.f,0.f,0.f,0.f};

    stageA(0, 0); stageB(0, 0);
    __syncthreads();
    for (int t = 0; t < 16; ++t) {
        int cur = t & 1;
        if (t < 15) { stageA(cur ^ 1, (t+1)*32); stageB(cur ^ 1, (t+1)*32); }
        short8 a8[4], b8[4];
        #pragma unroll
        for (int rt = 0; rt < 4; ++rt) {
            int row = wrow + rt*16 + lr;
            a8[rt] = *reinterpret_cast<const short8*>(
                (const char*)As + (size_t)cur*8192 + h*2048 + row*16);
        }
        #pragma unroll
        for (int ct = 0; ct < 4; ++ct) {
            int col = wcol + ct*16 + lr;
            int c = h ^ (col & 3);
            b8[ct] = *reinterpret_cast<const short8*>(
                (const char*)Bs + (size_t)cur*8192 + col*64 + c*16);
        }
        #pragma unroll
        for (int rt = 0; rt < 4; ++rt)
            #pragma unroll
            for (int ct = 0; ct < 4; ++ct)
                acc[rt][ct] = __builtin_amdgcn_mfma_f32_16x16x32_bf16(a8[rt], b8[ct], acc[rt][ct], 0, 0, 0);
        __syncthreads();
    }

    // epilogue: rowdot + GBbf store (z even)
    #pragma unroll
    for (int rt = 0; rt < 4; ++rt) {
        #pragma unroll
        for (int r = 0; r < 4; ++r) {
            int row = wrow + rt*16 + h*4 + r;
            float v = 0.f;
            #pragma unroll
            for (int ct = 0; ct < 4; ++ct) {
                int col = wcol + ct*16 + lr;
                float cv = acc[rt][ct][r];
                float xv = bf2f(Xh[(size_t)(i0+row)*DIM + j0 + col]);
                v = fmaf(cv, xv, v);
                if ((z & 1) == 0)
                    GBbf[((size_t)((z>>1)*SEQ + i0 + row))*DIM + j0 + col] = f2bfh(cv);
            }
            v += __shfl_xor(v, 1); v += __shfl_xor(v, 2);
            v += __shfl_xor(v, 4); v += __shfl_xor(v, 8);
            if (lr == 0) atomicAdd(&pX[(size_t)z*SEQ + i0 + row], 0.5f*v);
        }
    }
}

// ---------------- band via MFMA -> row-major fp32 taps Kt/Kc + Dt (verified r7) ----------------
__launch_bounds__(64)
__global__ void kband3(const ushort* __restrict__ GBbf, const ushort* __restrict__ Xbf,
                       const float* __restrict__ pX,
                       float* __restrict__ Ktb, float* __restrict__ Kcb,
                       float* __restrict__ Dt) {
    int g = blockIdx.y;
    int i0 = blockIdx.x * 16;
    int l = threadIdx.x;
    const ushort* A = GBbf + (size_t)g*SEQ*DIM;
    const ushort* Y = Xbf + (size_t)(1 + 2*g)*SEQ*DIM;      // Q for g0, S for g1
    const float* pM = pX + (size_t)(2*g)*SEQ;
    const float* qM = pX + (size_t)(2*g+1)*SEQ;
    int jbase = i0 - BW;
    int arow = i0 + (l & 15);
    int koff = (l >> 4) * 8;
    int jcl[4];
    #pragma unroll
    for (int ct = 0; ct < 4; ++ct) {
        int j = jbase + ct*16 + (l & 15);
        jcl[ct] = min(max(j, 0), SEQ-1);
    }
    f32x4 acc[4];
    #pragma unroll
    for (int ct = 0; ct < 4; ++ct) acc[ct] = (f32x4){0.f,0.f,0.f,0.f};
    #pragma unroll
    for (int ks = 0; ks < 16; ++ks) {
        int kk = ks*32 + koff;
        short8 af = *reinterpret_cast<const short8*>(&A[(size_t)arow*DIM + kk]);
        #pragma unroll
        for (int ct = 0; ct < 4; ++ct) {
            short8 bf = *reinterpret_cast<const short8*>(&Y[(size_t)jcl[ct]*DIM + kk]);
            acc[ct] = __builtin_amdgcn_mfma_f32_16x16x32_bf16(af, bf, acc[ct], 0, 0, 0);
        }
    }
    #pragma unroll
    for (int ct = 0; ct < 4; ++ct) {
        #pragma unroll
        for (int r = 0; r < 4; ++r) {
            int i = i0 + (l >> 4)*4 + r;
            int j = jbase + ct*16 + (l & 15);
            int d = j - i;
            if (d >= -BW && d <= BW && j >= 0 && j < SEQ) {
                float dist = pM[i] + qM[j] - acc[ct][r];
                float fd = (float)d;
                float rel = fd * (1.0f/4096.0f);
                float cd = -0.91893853f - 0.25f*fd*fd + 1e-4f/(rel*rel + 1.0f);
                float Kv = expf(cd - dist*1e-3f);
                Ktb[((size_t)g*SEQ + i)*TW + (d + BW)] = Kv;
                Kcb[((size_t)g*SEQ + j)*TW + (BW - d)] = Kv;
                Dt [((size_t)g*SEQ + i)*TW + (d + BW)] = dist;
            }
        }
    }
}

// ---------------- Sinkhorn: fused banded matvec chain; last launch folds final contraction ----------------
#define SR3  32
#define SB3  544          // covers range0 (512 max at nsteps=10) + tap-pad overread
#define NB_SINK 128       // blocks per g
#define TOTB (2*NB_SINK)
__launch_bounds__(256)
__global__ void ksink4(const float* __restrict__ Ktb, const float* __restrict__ Kcb,
                       const float* __restrict__ Dtb,
                       float* __restrict__ vecs, float* __restrict__ sc,
                       float* __restrict__ out,
                       int nsteps, int firstT, int alphaInit,
                       int vstep, int ustep, int cstep, int gated,
                       int inSlot, int outSlot, int dofinal) {
    int g = blockIdx.y;
    bool skip = false;
    if (gated && sc[g] < 1e-5f) {        // early-converged: freeze u,v
        if (!dofinal) return;
        skip = true;
    }
    int r0 = blockIdx.x * SR3;
    int ext = 24 * nsteps;
    __shared__ float bufA[SB3];
    __shared__ float bufB[SB3];
    __shared__ float vsave[SB3];
    __shared__ float red[256];
    float* bin = bufA;
    float* bout = bufB;
    if (!skip) {
        int base = r0 - ext;
        int range0 = SR3 + 2*ext;
        const float* vin = vecs + (size_t)(inSlot*2 + g)*VSTR;
        for (int L = threadIdx.x; L < SB3; L += 256) {
            int gr = base + L;
            float v = 0.f;
            if (L < range0 && gr >= 0 && gr < SEQ)
                v = alphaInit ? (gr+1)*INV_N : vin[VOFF + gr];
            bufA[L] = v;
            bufB[L] = 0.f;
        }
        __syncthreads();
        float critloc = 0.f;
        for (int m = 0; m < nsteps; ++m) {
            int e = 24*(nsteps - 1 - m);
            int lo = ext - e;
            int cnt = SR3 + 2*e;
            int typeT = firstT ^ (m & 1);
            const float* tap0 = (typeT ? Kcb : Ktb) + (size_t)g*SEQ*TW;
            for (int t = threadIdx.x; t < cnt; t += 256) {
                int L = lo + t;
                int gr = base + L;
                float o = 0.f;
                if (gr >= 0 && gr < SEQ) {
                    const float* tap = tap0 + (size_t)gr*TW;
                    float s = 0.f;
                    #pragma unroll
                    for (int c = 0; c < 14; ++c) {
                        float4 k4 = *reinterpret_cast<const float4*>(tap + c*4);
                        s = fmaf(k4.x, bin[L + c*4 + 0 - BW], s);
                        s = fmaf(k4.y, bin[L + c*4 + 1 - BW], s);
                        s = fmaf(k4.z, bin[L + c*4 + 2 - BW], s);
                        s = fmaf(k4.w, bin[L + c*4 + 3 - BW], s);
                    }
                    float ab = (gr+1)*INV_N;      // alpha == beta (m==n)
                    o = ab * __builtin_amdgcn_rcpf(s);
                    if (m == vstep) {
                        vecs[(size_t)(4 + g)*VSTR + VOFF + gr] = o;      // v slot
                        if (cstep >= 0) vsave[L] = o;
                    }
                    if (m == ustep)
                        vecs[(size_t)g*VSTR + VOFF + gr] = o;            // u slot
                    if (m == cstep)
                        critloc += fabsf(vsave[L]*s - ab);
                }
                bout[L] = o;
            }
            __syncthreads();
            float* tmp = bin; bin = bout; bout = tmp;
        }
        if (threadIdx.x < SR3) {
            int gr = r0 + threadIdx.x;
            vecs[(size_t)(outSlot*2 + g)*VSTR + VOFF + gr] = bin[ext + threadIdx.x];
        }
        if (cstep >= 0) {
            red[threadIdx.x] = critloc;
            __syncthreads();
            for (int s2 = 128; s2 > 0; s2 >>= 1) {
                if (threadIdx.x < s2) red[threadIdx.x] += red[threadIdx.x + s2];
                __syncthreads();
            }
            if (threadIdx.x == 0) atomicAdd(&sc[g], red[0]);
        }
    }
    if (!dofinal) return;

    // ---- final contraction: S_g += sum_i u_i * sum_t Kt[i][t]*Dt[i][t]*v[i+t-BW] ----
    // Non-skip: u = bin[ext+t] (step 41 output), v = bout (step 40 output, covers r0-24..r0+55).
    float partial = 0.f;
    if (threadIdx.x < SR3) {
        int i = r0 + threadIdx.x;
        const float* kt = Ktb + ((size_t)g*SEQ + i)*TW;
        const float* dt = Dtb + ((size_t)g*SEQ + i)*TW;
        float ssum = 0.f;
        if (!skip) {
            int Lb = ext + threadIdx.x;
            #pragma unroll
            for (int c = 0; c < 14; ++c) {
                float4 k4 = *reinterpret_cast<const float4*>(kt + c*4);
                float4 d4 = *reinterpret_cast<const float4*>(dt + c*4);
                ssum += k4.x * d4.x * bout[Lb + c*4 + 0 - BW];
                ssum += k4.y * d4.y * bout[Lb + c*4 + 1 - BW];
                ssum += k4.z * d4.z * bout[Lb + c*4 + 2 - BW];
                ssum += k4.w * d4.w * bout[Lb + c*4 + 3 - BW];
            }
            partial = ssum * bin[Lb];
        } else {
            const float* u = vecs + (size_t)g*VSTR + VOFF;
            const float* v = vecs + (size_t)(4 + g)*VSTR + VOFF;
            #pragma unroll
            for (int c = 0; c < 14; ++c) {
                float4 k4 = *reinterpret_cast<const float4*>(kt + c*4);
                float4 d4 = *reinterpret_cast<const float4*>(dt + c*4);
                ssum += k4.x * d4.x * v[i + c*4 + 0 - BW];
                ssum += k4.y * d4.y * v[i + c*4 + 1 - BW];
                ssum += k4.z * d4.z * v[i + c*4 + 2 - BW];
                ssum += k4.w * d4.w * v[i + c*4 + 3 - BW];
            }
            partial = ssum * u[i];
        }
    }
    __syncthreads();
    red[threadIdx.x] = partial;
    __syncthreads();
    for (int s2 = 128; s2 > 0; s2 >>= 1) {
        if (threadIdx.x < s2) red[threadIdx.x] += red[threadIdx.x + s2];
        __syncthreads();
    }
    if (threadIdx.x == 0) {
        atomicAdd(&sc[2+g], red[0]);
        __threadfence();
        unsigned old = atomicAdd((unsigned*)&sc[4], 1u);
        if (old == TOTB - 1) {
            __threadfence();
            out[0] = sc[2] - sc[3];
        }
    }
}

extern "C" void kernel_launch(void* const* d_in, const int* in_sizes, int n_in,
                              void* d_out, int out_size, void* d_ws, size_t ws_size,
                              hipStream_t stream) {
    const float* P = (const float*)d_in[0];
    const float* Q = (const float*)d_in[1];
    const float* R = (const float*)d_in[2];
    const float* S = (const float*)d_in[3];
    const float* M = (const float*)d_in[4];
    float* ws = (float*)d_ws;
    if (ws_size < (size_t)WS_FLOATS * sizeof(float)) return;

    float*  Ktb = ws + OFF_KT;
    float*  Kcb = ws + OFF_KC;
    float*  Dt  = ws + OFF_DT;
    float*  vec = ws + OFF_VEC;
    float*  pX  = ws + OFF_PX;
    float*  sc  = ws + OFF_SC;
    ushort* Bbf = (ushort*)(ws + OFF_BBF);
    ushort* Xbf = (ushort*)(ws + OFF_XBF);
    ushort* GBbf= (ushort*)(ws + OFF_GBF);
    float*  outp= (float*)d_out;

    kprep <<<dim3(PREP_BLOCKS), dim3(256), 0, stream>>>(P, Q, R, S, M, ws);
    kgemm5<<<dim3(32, 4, 4),    dim3(256), 0, stream>>>(Xbf, Bbf, GBbf, pX);
    kband3<<<dim3(256, 2),      dim3(64),  0, stream>>>(GBbf, Xbf, pX, Ktb, Kcb, Dt);

    // Sinkhorn: 42 banded matvecs in 5 fused launches; last folds final contraction + output.
    // Global steps: even=T, odd=N. Slots: 0=u, 1=y, 2=v.
    // A: steps 0-4 (T,N,T->v2,N->u2,T->crit1), out y
    ksink4<<<dim3(NB_SINK,2), dim3(256), 0, stream>>>(Ktb, Kcb, Dt, vec, sc, outp,
                                                       5, 1, 1,  2,  3,  4, 0, 0, 1, 0);
    // B: steps 5-13 (starts N)
    ksink4<<<dim3(NB_SINK,2), dim3(256), 0, stream>>>(Ktb, Kcb, Dt, vec, sc, outp,
                                                       9, 0, 0, -1, -1, -1, 1, 1, 1, 0);
    // C: steps 14-22 (starts T)
    ksink4<<<dim3(NB_SINK,2), dim3(256), 0, stream>>>(Ktb, Kcb, Dt, vec, sc, outp,
                                                       9, 1, 0, -1, -1, -1, 1, 1, 1, 0);
    // D: steps 23-31 (starts N)
    ksink4<<<dim3(NB_SINK,2), dim3(256), 0, stream>>>(Ktb, Kcb, Dt, vec, sc, outp,
                                                       9, 0, 0, -1, -1, -1, 1, 1, 1, 0);
    // E: steps 32-41 (starts T; v2' at local m=8, u2' out slot0) + final contraction + output
    ksink4<<<dim3(NB_SINK,2), dim3(256), 0, stream>>>(Ktb, Kcb, Dt, vec, sc, outp,
                                                      10, 1, 0,  8, -1, -1, 1, 1, 0, 1);
}

// Round 10
// 130.129 us; speedup vs baseline: 2.7149x; 1.2991x over previous
//
#include <hip/hip_runtime.h>
#include <hip/hip_bf16.h>
#include <math.h>

// Problem constants
#define SEQ   4096
#define DIM   512
#define BW    24            // band half-width: prior underflows fp32 beyond |i-j|~20
#define NDIAG 49            // 2*BW+1
#define TW    56            // padded tap width (49 -> 56 for 16B alignment)
#define VSTR  4608          // padded row stride for vectors (4096 + 512)
#define VOFF  256           // data offset inside padded row (zeros on both sides)
#define INV_N (1.0f/4096.0f)

// ws layout in floats
#define OFF_KT   0                          // Kt fp32 [2][4096][56]: taps for N-step
#define SZ_T     (2*SEQ*TW)                 // 458752
#define OFF_KC   (OFF_KT + SZ_T)            // Kc fp32 [2][4096][56]: taps for T-step
#define OFF_DT   (OFF_KC + SZ_T)            // Dt fp32 [2][4096][56]
#define OFF_VEC  (OFF_DT + SZ_T)            // 6 padded vectors: u(g0,g1), y(g0,g1), v(g0,g1)
#define SZ_VEC   (6*VSTR)
#define OFF_PX   (OFF_VEC + SZ_VEC)         // pMp for P,Q,R,S : 4 x 4096
#define SZ_PX    (4*SEQ)
#define OFF_SC   (OFF_PX + SZ_PX)           // scalars: [0,1]=crit, [2,3]=S, [4]=done-counter
#define SZ_SC    16
#define OFF_BBF  (OFF_SC + SZ_SC)           // Bsym bf16 512x512
#define SZ_BBF   (DIM*DIM/2)
#define OFF_XBF  (OFF_BBF + SZ_BBF)         // P,Q,R,S bf16: 4 x 4096 x 512
#define SZ_XBF   (4*SEQ*DIM/2)
#define OFF_GBF  (OFF_XBF + SZ_XBF)         // P@B, R@B bf16
#define SZ_GBF   (2*SEQ*DIM/2)
#define WS_FLOATS (OFF_GBF + SZ_GBF)

typedef __attribute__((ext_vector_type(8))) short short8;
typedef __attribute__((ext_vector_type(4))) float f32x4;

__device__ __forceinline__ ushort f2bfh(float f) {
    __hip_bfloat16 h = __float2bfloat16(f);      // native v_cvt (RNE)
    return *reinterpret_cast<ushort*>(&h);
}
__device__ __forceinline__ float bf2f(ushort u) {
    union { unsigned u; float f; } w; w.u = ((unsigned)u) << 16; return w.f;
}

__device__ __forceinline__ void gload16(void* lds, const void* g) {
    __builtin_amdgcn_global_load_lds(
        (const __attribute__((address_space(1))) unsigned int*)g,
        (__attribute__((address_space(3))) unsigned int*)lds,
        16, 0, 0);
}

// ---------------- fused prep (verified r7) ----------------
#define ZQUADS (OFF_BBF/4)
#define ZBLK   ((ZQUADS + 255)/256)
#define BBLK   1024
#define CBLK   8192
#define PREP_BLOCKS (ZBLK + BBLK + CBLK)

__global__ void kprep(const float* __restrict__ P, const float* __restrict__ Q,
                      const float* __restrict__ R, const float* __restrict__ S,
                      const float* __restrict__ M, float* __restrict__ ws) {
    int b = blockIdx.x, tid = threadIdx.x;
    if (b < ZBLK) {
        int q = b*256 + tid;
        if (q < ZQUADS)
            *reinterpret_cast<float4*>(&ws[(size_t)q*4]) = (float4){0.f,0.f,0.f,0.f};
    } else if (b < ZBLK + BBLK) {
        int idx = (b - ZBLK)*256 + tid;
        int d = idx >> 9, e = idx & 511;
        ((ushort*)(ws + OFF_BBF))[idx] = f2bfh(M[d*DIM + e] + M[e*DIM + d]);
    } else {
        int cb = b - (ZBLK + BBLK);
        int z = cb >> 11;
        const float* src = (z==0) ? P : (z==1) ? Q : (z==2) ? R : S;
        size_t idx = ((size_t)(cb & 2047)*256 + tid)*4;
        float4 v = *reinterpret_cast<const float4*>(&src[idx]);
        ushort4 o;
        o.x = f2bfh(v.x); o.y = f2bfh(v.y); o.z = f2bfh(v.z); o.w = f2bfh(v.w);
        *reinterpret_cast<ushort4*>(((ushort*)(ws + OFF_XBF)) + (size_t)z*SEQ*DIM + idx) = o;
    }
}

// ---------------- MFMA GEMM, all-bf16 A, 2-phase pipelined (verified r7, unchanged) ----------------
__launch_bounds__(256, 4)
__global__ void kgemm5(const ushort* __restrict__ Xbf, const ushort* __restrict__ Bbf,
                       ushort* __restrict__ GBbf, float* __restrict__ pX) {
    int z = blockIdx.z;
    const ushort* Xh = Xbf + (size_t)z*SEQ*DIM;
    int i0 = blockIdx.x * 128;
    int j0 = blockIdx.y * 128;
    __shared__ ushort As[2*4096];      // 2 x 8KB, chunk-major
    __shared__ ushort Bs[2*4096];      // 2 x 8KB, rows 64B, chunk^=(col&3)
    int tid = threadIdx.x, wv = tid >> 6, l = tid & 63;
    int h = l >> 4, lr = l & 15;
    int wrow = (wv >> 1)*64, wcol = (wv & 1)*64;

    auto stageA = [&](int buf, int kc) {
        #pragma unroll
        for (int s2 = 0; s2 < 2; ++s2) {
            int seg = wv*2 + s2;               // chunk = seg>>1, rowhalf = seg&1
            gload16((char*)As + (size_t)buf*8192 + seg*1024,
                    &Xh[(size_t)(i0 + (seg&1)*64 + l)*DIM + kc + (seg>>1)*8]);
        }
    };
    auto stageB = [&](int buf, int kc) {
        #pragma unroll
        for (int s2 = 0; s2 < 2; ++s2) {
            int seg = wv*2 + s2;
            int col = seg*16 + (l >> 2);
            int cs = (l & 3) ^ (col & 3);
            gload16((char*)Bs + (size_t)buf*8192 + seg*1024,
                    &Bbf[(size_t)(j0+col)*DIM + kc + cs*8]);
        }
    };

    f32x4 acc[4][4];
    #pragma unroll
    for (int a = 0; a < 4; ++a)
        #pragma unroll
        for (int b = 0; b < 4; ++b) acc[a][b] = (f32x4){0.f,0.f,0.f,0.f};

    stageA(0, 0); stageB(0, 0);
    __syncthreads();
    for (int t = 0; t < 16; ++t) {
        int cur = t & 1;
        if (t < 15) { stageA(cur ^ 1, (t+1)*32); stageB(cur ^ 1, (t+1)*32); }
        short8 a8[4], b8[4];
        #pragma unroll
        for (int rt = 0; rt < 4; ++rt) {
            int row = wrow + rt*16 + lr;
            a8[rt] = *reinterpret_cast<const short8*>(
                (const char*)As + (size_t)cur*8192 + h*2048 + row*16);
        }
        #pragma unroll
        for (int ct = 0; ct < 4; ++ct) {
            int col = wcol + ct*16 + lr;
            int c = h ^ (col & 3);
            b8[ct] = *reinterpret_cast<const short8*>(
                (const char*)Bs + (size_t)cur*8192 + col*64 + c*16);
        }
        #pragma unroll
        for (int rt = 0; rt < 4; ++rt)
            #pragma unroll
            for (int ct = 0; ct < 4; ++ct)
                acc[rt][ct] = __builtin_amdgcn_mfma_f32_16x16x32_bf16(a8[rt], b8[ct], acc[rt][ct], 0, 0, 0);
        __syncthreads();
    }

    // epilogue: rowdot + GBbf store (z even)
    #pragma unroll
    for (int rt = 0; rt < 4; ++rt) {
        #pragma unroll
        for (int r = 0; r < 4; ++r) {
            int row = wrow + rt*16 + h*4 + r;
            float v = 0.f;
            #pragma unroll
            for (int ct = 0; ct < 4; ++ct) {
                int col = wcol + ct*16 + lr;
                float cv = acc[rt][ct][r];
                float xv = bf2f(Xh[(size_t)(i0+row)*DIM + j0 + col]);
                v = fmaf(cv, xv, v);
                if ((z & 1) == 0)
                    GBbf[((size_t)((z>>1)*SEQ + i0 + row))*DIM + j0 + col] = f2bfh(cv);
            }
            v += __shfl_xor(v, 1); v += __shfl_xor(v, 2);
            v += __shfl_xor(v, 4); v += __shfl_xor(v, 8);
            if (lr == 0) atomicAdd(&pX[(size_t)z*SEQ + i0 + row], 0.5f*v);
        }
    }
}

// ---------------- band via MFMA -> row-major fp32 taps Kt/Kc + Dt (verified r7, unchanged) ----------------
__launch_bounds__(64)
__global__ void kband3(const ushort* __restrict__ GBbf, const ushort* __restrict__ Xbf,
                       const float* __restrict__ pX,
                       float* __restrict__ Ktb, float* __restrict__ Kcb,
                       float* __restrict__ Dt) {
    int g = blockIdx.y;
    int i0 = blockIdx.x * 16;
    int l = threadIdx.x;
    const ushort* A = GBbf + (size_t)g*SEQ*DIM;
    const ushort* Y = Xbf + (size_t)(1 + 2*g)*SEQ*DIM;      // Q for g0, S for g1
    const float* pM = pX + (size_t)(2*g)*SEQ;
    const float* qM = pX + (size_t)(2*g+1)*SEQ;
    int jbase = i0 - BW;
    int arow = i0 + (l & 15);
    int koff = (l >> 4) * 8;
    int jcl[4];
    #pragma unroll
    for (int ct = 0; ct < 4; ++ct) {
        int j = jbase + ct*16 + (l & 15);
        jcl[ct] = min(max(j, 0), SEQ-1);
    }
    f32x4 acc[4];
    #pragma unroll
    for (int ct = 0; ct < 4; ++ct) acc[ct] = (f32x4){0.f,0.f,0.f,0.f};
    #pragma unroll
    for (int ks = 0; ks < 16; ++ks) {
        int kk = ks*32 + koff;
        short8 af = *reinterpret_cast<const short8*>(&A[(size_t)arow*DIM + kk]);
        #pragma unroll
        for (int ct = 0; ct < 4; ++ct) {
            short8 bf = *reinterpret_cast<const short8*>(&Y[(size_t)jcl[ct]*DIM + kk]);
            acc[ct] = __builtin_amdgcn_mfma_f32_16x16x32_bf16(af, bf, acc[ct], 0, 0, 0);
        }
    }
    #pragma unroll
    for (int ct = 0; ct < 4; ++ct) {
        #pragma unroll
        for (int r = 0; r < 4; ++r) {
            int i = i0 + (l >> 4)*4 + r;
            int j = jbase + ct*16 + (l & 15);
            int d = j - i;
            if (d >= -BW && d <= BW && j >= 0 && j < SEQ) {
                float dist = pM[i] + qM[j] - acc[ct][r];
                float fd = (float)d;
                float rel = fd * (1.0f/4096.0f);
                float cd = -0.91893853f - 0.25f*fd*fd + 1e-4f/(rel*rel + 1.0f);
                float Kv = expf(cd - dist*1e-3f);
                Ktb[((size_t)g*SEQ + i)*TW + (d + BW)] = Kv;
                Kcb[((size_t)g*SEQ + j)*TW + (BW - d)] = Kv;
                Dt [((size_t)g*SEQ + i)*TW + (d + BW)] = dist;
            }
        }
    }
}

// ---------------- Sinkhorn: 512-thread blocks, 1 slot/thread, cross-step register tap prefetch ----
#define SR3  32
#define SB3  384          // max range0 = 368 (nsteps=7); max read idx 374
#define NB_SINK 128       // blocks per g
#define TOTB (2*NB_SINK)
__launch_bounds__(512)
__global__ void ksink5(const float* __restrict__ Ktb, const float* __restrict__ Kcb,
                       const float* __restrict__ Dtb,
                       float* __restrict__ vecs, float* __restrict__ sc,
                       float* __restrict__ out,
                       int nsteps, int firstT, int alphaInit,
                       int vstep, int ustep, int cstep, int gated,
                       int inSlot, int outSlot, int dofinal) {
    int g = blockIdx.y;
    bool skip = false;
    if (gated && sc[g] < 1e-5f) {        // early-converged: freeze u,v
        if (!dofinal) return;
        skip = true;
    }
    int r0 = blockIdx.x * SR3;
    int ext = 24 * nsteps;
    int t = threadIdx.x;
    __shared__ float bufA[SB3];
    __shared__ float bufB[SB3];
    __shared__ float vsave[SB3];
    __shared__ float red[512];
    float* bin = bufA;
    float* bout = bufB;
    float critloc = 0.f;

    // tap row pointer for step m, this thread's slot (clamped; guard at use)
    auto tapptr = [&](int m) -> const float* {
        int typeT = firstT ^ (m & 1);
        int gr = r0 - 24*(nsteps - 1 - m) + t;
        int grc = min(max(gr, 0), SEQ - 1);
        return (typeT ? Kcb : Ktb) + ((size_t)g*SEQ + grc)*TW;
    };

    float4 tpA[14], tpB[14];

    if (!skip) {
        int base = r0 - ext;
        int range0 = SR3 + 2*ext;
        const float* vin = vecs + (size_t)(inSlot*2 + g)*VSTR;
        // prefetch step-0 taps (overlaps with LDS fill)
        if (t < range0) {
            const float* tp = tapptr(0);
            #pragma unroll
            for (int c = 0; c < 14; ++c) tpA[c] = *reinterpret_cast<const float4*>(tp + c*4);
        }
        for (int L = t; L < SB3; L += 512) {
            int gr = base + L;
            float v = 0.f;
            if (L < range0 && gr >= 0 && gr < SEQ)
                v = alphaInit ? (gr+1)*INV_N : vin[VOFF + gr];
            bufA[L] = v;
            bufB[L] = 0.f;
        }
        __syncthreads();

        // one step: consume `cur` taps, prefetch `nxt` taps for step m+1
        auto step = [&](float4 (&cur)[14], float4 (&nxt)[14], int m) {
            int e = 24*(nsteps - 1 - m);
            int cnt = SR3 + 2*e;
            int L = (ext - e) + t;
            int gr = base + L;
            if ((m + 1 < nsteps) && (t < cnt - 48)) {      // cnt_{m+1} = cnt - 48
                const float* tp = tapptr(m + 1);
                #pragma unroll
                for (int c = 0; c < 14; ++c) nxt[c] = *reinterpret_cast<const float4*>(tp + c*4);
            }
            float o = 0.f;
            if (t < cnt && gr >= 0 && gr < SEQ) {
                float s = 0.f;
                #pragma unroll
                for (int c = 0; c < 14; ++c) {
                    s = fmaf(cur[c].x, bin[L + c*4 + 0 - BW], s);
                    s = fmaf(cur[c].y, bin[L + c*4 + 1 - BW], s);
                    s = fmaf(cur[c].z, bin[L + c*4 + 2 - BW], s);
                    s = fmaf(cur[c].w, bin[L + c*4 + 3 - BW], s);
                }
                float ab = (gr+1)*INV_N;      // alpha == beta (m==n)
                o = ab * __builtin_amdgcn_rcpf(s);
                if (m == vstep) {
                    vecs[(size_t)(4 + g)*VSTR + VOFF + gr] = o;      // v slot
                    if (cstep >= 0) vsave[L] = o;
                }
                if (m == ustep)
                    vecs[(size_t)g*VSTR + VOFF + gr] = o;            // u slot
                if (m == cstep)
                    critloc += fabsf(vsave[L]*s - ab);
            }
            if (t < cnt) bout[L] = o;
            __syncthreads();
            float* tmp = bin; bin = bout; bout = tmp;
        };

        for (int m = 0; m < nsteps; ++m) {
            if ((m & 1) == 0) step(tpA, tpB, m);
            else              step(tpB, tpA, m);
        }

        if (t < SR3) {
            int gr = r0 + t;
            vecs[(size_t)(outSlot*2 + g)*VSTR + VOFF + gr] = bin[ext + t];
        }
        if (cstep >= 0) {
            red[t] = critloc;
            __syncthreads();
            for (int s2 = 256; s2 > 0; s2 >>= 1) {
                if (t < s2) red[t] += red[t + s2];
                __syncthreads();
            }
            if (t == 0) atomicAdd(&sc[g], red[0]);
        }
    }
    if (!dofinal) return;

    // ---- final contraction: S_g += sum_i u_i * sum_t Kt[i][t]*Dt[i][t]*v[i+t-BW] ----
    // Non-skip: u = bin[ext+t] (last step output), v = bout (prev step, covers r0-24..r0+55).
    float partial = 0.f;
    if (t < SR3) {
        int i = r0 + t;
        const float* kt = Ktb + ((size_t)g*SEQ + i)*TW;
        const float* dt = Dtb + ((size_t)g*SEQ + i)*TW;
        float ssum = 0.f;
        if (!skip) {
            int Lb = ext + t;
            #pragma unroll
            for (int c = 0; c < 14; ++c) {
                float4 k4 = *reinterpret_cast<const float4*>(kt + c*4);
                float4 d4 = *reinterpret_cast<const float4*>(dt + c*4);
                ssum += k4.x * d4.x * bout[Lb + c*4 + 0 - BW];
                ssum += k4.y * d4.y * bout[Lb + c*4 + 1 - BW];
                ssum += k4.z * d4.z * bout[Lb + c*4 + 2 - BW];
                ssum += k4.w * d4.w * bout[Lb + c*4 + 3 - BW];
            }
            partial = ssum * bin[Lb];
        } else {
            const float* u = vecs + (size_t)g*VSTR + VOFF;
            const float* v = vecs + (size_t)(4 + g)*VSTR + VOFF;
            #pragma unroll
            for (int c = 0; c < 14; ++c) {
                float4 k4 = *reinterpret_cast<const float4*>(kt + c*4);
                float4 d4 = *reinterpret_cast<const float4*>(dt + c*4);
                ssum += k4.x * d4.x * v[i + c*4 + 0 - BW];
                ssum += k4.y * d4.y * v[i + c*4 + 1 - BW];
                ssum += k4.z * d4.z * v[i + c*4 + 2 - BW];
                ssum += k4.w * d4.w * v[i + c*4 + 3 - BW];
            }
            partial = ssum * u[i];
        }
    }
    __syncthreads();
    red[t] = partial;
    __syncthreads();
    for (int s2 = 256; s2 > 0; s2 >>= 1) {
        if (t < s2) red[t] += red[t + s2];
        __syncthreads();
    }
    if (t == 0) {
        atomicAdd(&sc[2+g], red[0]);
        __threadfence();
        unsigned old = atomicAdd((unsigned*)&sc[4], 1u);
        if (old == TOTB - 1) {
            __threadfence();
            out[0] = sc[2] - sc[3];
        }
    }
}

extern "C" void kernel_launch(void* const* d_in, const int* in_sizes, int n_in,
                              void* d_out, int out_size, void* d_ws, size_t ws_size,
                              hipStream_t stream) {
    const float* P = (const float*)d_in[0];
    const float* Q = (const float*)d_in[1];
    const float* R = (const float*)d_in[2];
    const float* S = (const float*)d_in[3];
    const float* M = (const float*)d_in[4];
    float* ws = (float*)d_ws;
    if (ws_size < (size_t)WS_FLOATS * sizeof(float)) return;

    float*  Ktb = ws + OFF_KT;
    float*  Kcb = ws + OFF_KC;
    float*  Dt  = ws + OFF_DT;
    float*  vec = ws + OFF_VEC;
    float*  pX  = ws + OFF_PX;
    float*  sc  = ws + OFF_SC;
    ushort* Bbf = (ushort*)(ws + OFF_BBF);
    ushort* Xbf = (ushort*)(ws + OFF_XBF);
    ushort* GBbf= (ushort*)(ws + OFF_GBF);
    float*  outp= (float*)d_out;

    kprep <<<dim3(PREP_BLOCKS), dim3(256), 0, stream>>>(P, Q, R, S, M, ws);
    kgemm5<<<dim3(32, 4, 4),    dim3(256), 0, stream>>>(Xbf, Bbf, GBbf, pX);
    kband3<<<dim3(256, 2),      dim3(64),  0, stream>>>(GBbf, Xbf, pX, Ktb, Kcb, Dt);

    // Sinkhorn: 42 banded matvecs in 7 fused launches (r7-optimal schedule);
    // last launch folds final contraction + output. Slots: 0=u, 1=y, 2=v.
    // A: steps 0-4 (T,N,T->v2,N->u2,T->crit1), out y
    ksink5<<<dim3(NB_SINK,2), dim3(512), 0, stream>>>(Ktb, Kcb, Dt, vec, sc, outp,
                                                       5, 1, 1,  2,  3,  4, 0, 0, 1, 0);
    // bodies: 5 x 6 steps (N,T alternating), gated on crit1
    ksink5<<<dim3(NB_SINK,2), dim3(512), 0, stream>>>(Ktb, Kcb, Dt, vec, sc, outp,
                                                       6, 0, 0, -1, -1, -1, 1, 1, 1, 0);
    ksink5<<<dim3(NB_SINK,2), dim3(512), 0, stream>>>(Ktb, Kcb, Dt, vec, sc, outp,
                                                       6, 0, 0, -1, -1, -1, 1, 1, 1, 0);
    ksink5<<<dim3(NB_SINK,2), dim3(512), 0, stream>>>(Ktb, Kcb, Dt, vec, sc, outp,
                                                       6, 0, 0, -1, -1, -1, 1, 1, 1, 0);
    ksink5<<<dim3(NB_SINK,2), dim3(512), 0, stream>>>(Ktb, Kcb, Dt, vec, sc, outp,
                                                       6, 0, 0, -1, -1, -1, 1, 1, 1, 0);
    ksink5<<<dim3(NB_SINK,2), dim3(512), 0, stream>>>(Ktb, Kcb, Dt, vec, sc, outp,
                                                       6, 0, 0, -1, -1, -1, 1, 1, 1, 0);
    // last: 7 steps incl. check2 (T->v2' at local m=5, N->u2' out slot0) + final + output
    ksink5<<<dim3(NB_SINK,2), dim3(512), 0, stream>>>(Ktb, Kcb, Dt, vec, sc, outp,
                                                       7, 0, 0,  5, -1, -1, 1, 1, 0, 1);
}